// Round 1
// baseline (17918.167 us; speedup 1.0000x reference)
//
#include <hip/hip_runtime.h>
#include <hip/hip_fp16.h>

// RNN: h_{t+1} = tanh(x_t*W_ih + b_ih + b_hh + h_t @ W_hh^T), T=1024 steps.
// Design: 256 WGs = 64 batches x 4 j-slices(128 each). 256 thr/WG (4 waves).
//  - W_hh slice (128 j x 512 k fp32 = 256KB) register-resident: 256 VGPR/thread
//    (thread owns j0=q*128+lane, j1=j0+64 over its wave's 128-k slice).
//  - h kept in LDS as fp16 (broadcast ds_read_b128 per wave = only its k-slice).
//  - per-step cross-WG all-gather of fp16 h slices via L3: relaxed AGENT-scope
//    data dwords + monotone release/acquire flag per WG, parity double-buffer.
//  - flags zeroed by hipMemsetAsync each call -> deterministic replays.

#define BB 64
#define TT 1024
#define HH 512
#define FSTRIDE 16  // flag padding: one flag per 64B line

__launch_bounds__(256, 1)
__global__ void rnn_persist(const float* __restrict__ x,      // [B,T]
                            const float* __restrict__ W_ih,   // [H]
                            const float* __restrict__ W_hh,   // [H,H]
                            const float* __restrict__ b_ih,   // [H]
                            const float* __restrict__ b_hh,   // [H]
                            const float* __restrict__ W_out,  // [H]
                            const float* __restrict__ b_out,  // [1]
                            float* __restrict__ out,          // [64 + B*H]
                            unsigned* __restrict__ flags,     // [B*4*FSTRIDE]
                            unsigned* __restrict__ hg)        // [2][B][4][64]
{
    const int b    = blockIdx.x >> 2;
    const int q    = blockIdx.x & 3;
    const int tid  = threadIdx.x;
    const int w    = tid >> 6;   // wave id 0..3 = k-slice
    const int lane = tid & 63;

    // h (fp16) for the whole hidden vector: 512 halves = 256 dwords.
    // slice q' occupies dwords [q'*64, q'*64+64)  == h[q'*128 .. q'*128+128)
    __shared__ __align__(16) unsigned h2[HH / 2];
    __shared__ float part[4][128];

    const int j0 = q * 128 + lane;   // first owned output row
    const int j1 = j0 + 64;          // second owned output row
    const int k0 = w * 128;          // this wave's k-slice base

    // ---- load weight slices into registers (one-time) ----
    float w0[128], w1[128];
    {
        const float4* r0 = reinterpret_cast<const float4*>(W_hh + (size_t)j0 * HH + k0);
        const float4* r1 = reinterpret_cast<const float4*>(W_hh + (size_t)j1 * HH + k0);
#pragma unroll
        for (int c = 0; c < 32; ++c) {
            float4 a = r0[c], d = r1[c];
            w0[4*c+0] = a.x; w0[4*c+1] = a.y; w0[4*c+2] = a.z; w0[4*c+3] = a.w;
            w1[4*c+0] = d.x; w1[4*c+1] = d.y; w1[4*c+2] = d.z; w1[4*c+3] = d.w;
        }
    }

    // reducer (wave 0) constants: lane handles j_local = 2*lane, 2*lane+1
    float wihA = 0.f, wihB = 0.f, bA = 0.f, bB = 0.f;
    if (w == 0) {
        const int ja = q * 128 + 2 * lane, jb = ja + 1;
        wihA = W_ih[ja]; wihB = W_ih[jb];
        bA = b_ih[ja] + b_hh[ja];
        bB = b_ih[jb] + b_hh[jb];
    }

    const int fbase = b * 4;
    float a0 = 0.f, a1 = 0.f;

#pragma unroll 1
    for (int t = 0; t < TT; ++t) {
        // ---- matvec partials over this wave's k-slice (h_0 = 0 -> skip at t=0) ----
        if (t > 0) {
            a0 = 0.f; a1 = 0.f;
            const uint4* hp = reinterpret_cast<const uint4*>(&h2[k0 >> 1]); // 8 halves/load
#pragma unroll
            for (int c = 0; c < 16; ++c) {
                const uint4 u = hp[c];
                {
                    const __half2 p = __builtin_bit_cast(__half2, u.x);
                    const float f0 = __low2float(p), f1 = __high2float(p);
                    a0 = fmaf(f0, w0[8*c+0], a0); a1 = fmaf(f0, w1[8*c+0], a1);
                    a0 = fmaf(f1, w0[8*c+1], a0); a1 = fmaf(f1, w1[8*c+1], a1);
                }
                {
                    const __half2 p = __builtin_bit_cast(__half2, u.y);
                    const float f0 = __low2float(p), f1 = __high2float(p);
                    a0 = fmaf(f0, w0[8*c+2], a0); a1 = fmaf(f0, w1[8*c+2], a1);
                    a0 = fmaf(f1, w0[8*c+3], a0); a1 = fmaf(f1, w1[8*c+3], a1);
                }
                {
                    const __half2 p = __builtin_bit_cast(__half2, u.z);
                    const float f0 = __low2float(p), f1 = __high2float(p);
                    a0 = fmaf(f0, w0[8*c+4], a0); a1 = fmaf(f0, w1[8*c+4], a1);
                    a0 = fmaf(f1, w0[8*c+5], a0); a1 = fmaf(f1, w1[8*c+5], a1);
                }
                {
                    const __half2 p = __builtin_bit_cast(__half2, u.w);
                    const float f0 = __low2float(p), f1 = __high2float(p);
                    a0 = fmaf(f0, w0[8*c+6], a0); a1 = fmaf(f0, w1[8*c+6], a1);
                    a0 = fmaf(f1, w0[8*c+7], a0); a1 = fmaf(f1, w1[8*c+7], a1);
                }
            }
        }
        part[w][lane]      = a0;
        part[w][lane + 64] = a1;
        __syncthreads();

        // ---- wave 0: reduce 4 k-partials, add xp, tanh, publish own slice ----
        if (w == 0) {
            const int jlA = 2 * lane, jlB = jlA + 1;
            float zA = (part[0][jlA] + part[1][jlA]) + (part[2][jlA] + part[3][jlA]);
            float zB = (part[0][jlB] + part[1][jlB]) + (part[2][jlB] + part[3][jlB]);
            const float xt = x[b * TT + t];
            zA = fmaf(xt, wihA, zA + bA);
            zB = fmaf(xt, wihB, zB + bB);
            const float hA = tanhf(zA);
            const float hB = tanhf(zB);
            const __half2 hh = __floats2half2_rn(hA, hB);
            const unsigned du = __builtin_bit_cast(unsigned, hh);
            h2[q * 64 + lane] = du;  // own slice locally
            __hip_atomic_store(&hg[(((t & 1) * BB + b) * 4 + q) * 64 + lane], du,
                               __ATOMIC_RELAXED, __HIP_MEMORY_SCOPE_AGENT);
            if (t == TT - 1) {
                out[64 + b * HH + q * 128 + jlA] = hA;
                out[64 + b * HH + q * 128 + jlB] = hB;
            }
        }
        // release flag: thread0's release orders wave0's data stores (wave-level vmcnt)
        if (tid == 0) {
            __hip_atomic_store(&flags[(fbase + q) * FSTRIDE], (unsigned)(t + 1),
                               __ATOMIC_RELEASE, __HIP_MEMORY_SCOPE_AGENT);
        }
        // ---- waves 1..3: gather the 3 partner slices for this step ----
        if (w > 0) {
            const int qp = (q + w) & 3;
            unsigned* fp = &flags[(fbase + qp) * FSTRIDE];
            while (__hip_atomic_load(fp, __ATOMIC_ACQUIRE, __HIP_MEMORY_SCOPE_AGENT)
                   < (unsigned)(t + 1)) {
                __builtin_amdgcn_s_sleep(1);
            }
            const unsigned dv =
                __hip_atomic_load(&hg[(((t & 1) * BB + b) * 4 + qp) * 64 + lane],
                                  __ATOMIC_RELAXED, __HIP_MEMORY_SCOPE_AGENT);
            h2[qp * 64 + lane] = dv;
        }
        __syncthreads();
    }

    // ---- epilogue: q==0 WG computes output[b] = h_last . W_out + b_out ----
    if (q == 0 && w == 0) {
        float s = 0.f;
        const __half* hl = reinterpret_cast<const __half*>(h2);
#pragma unroll
        for (int i = 0; i < 8; ++i)
            s = fmaf(__half2float(hl[lane * 8 + i]), W_out[lane * 8 + i], s);
#pragma unroll
        for (int off = 32; off; off >>= 1)
            s += __shfl_down(s, off, 64);
        if (lane == 0) out[b] = s + b_out[0];
    }
}

extern "C" void kernel_launch(void* const* d_in, const int* in_sizes, int n_in,
                              void* d_out, int out_size, void* d_ws, size_t ws_size,
                              hipStream_t stream) {
    const float* x     = (const float*)d_in[0];  // inputs [B,T,1]
    // d_in[1] = state (ignored; reference uses zero init)
    const float* W_ih  = (const float*)d_in[2];
    const float* W_hh  = (const float*)d_in[3];
    const float* b_ih  = (const float*)d_in[4];
    const float* b_hh  = (const float*)d_in[5];
    const float* W_out = (const float*)d_in[6];
    const float* b_out = (const float*)d_in[7];

    unsigned* flags = (unsigned*)d_ws;                 // 64*4*FSTRIDE dwords = 16KB
    unsigned* hg    = flags + BB * 4 * FSTRIDE;        // 2*64*4*64 dwords  = 128KB

    // flags must start at 0 every call (ws poisoned 0xAA once, never re-poisoned)
    hipMemsetAsync(flags, 0, BB * 4 * FSTRIDE * sizeof(unsigned), stream);

    rnn_persist<<<dim3(BB * 4), dim3(256), 0, stream>>>(
        x, W_ih, W_hh, b_ih, b_hh, W_out, b_out,
        (float*)d_out, flags, hg);
}

// Round 2
// 1279.077 us; speedup vs baseline: 14.0087x; 14.0087x over previous
//
#include <hip/hip_runtime.h>
#include <hip/hip_fp16.h>

// RNN h_{t+1} = tanh(x_t*W_ih + b_ih + b_hh + h_t @ W_hh^T), T=1024, B=64, H=512.
//
// Topology: 256 WGs = 4 j-slices x 64 batches (blockIdx = q*64 + b so a batch's
// 4 WGs share an XCD under round-robin dispatch). 256 thr/WG = 4 waves.
//  - W_hh slice (128 j x 512 k) register-resident as PACKED fp16: 128 VGPR/thr
//    (thread owns j0=lane, j1=lane+64 of the slice, over its wave's 128-k range).
//  - Exchange: single 8B atomic word {tag:32 | half2 h:32} per 2 h-values.
//    RELAXED device-scope load/store, equality poll on tag == t. One L3 round
//    trip per step; no flags, no fences. Parity double-buffer (tag t in slot t&1).
//  - Wave w polls exactly slice w (its k-range). Reduce/tanh/publish distributed:
//    lanes 0..15 of wave w handle output slots 16w..16w+15. ONE barrier per step.
//  - Skew safety: WG cannot publish t+2 before all consumers of its t-value have
//    read it (publish t+2 <- own barrier(t+1) <- polled t+1 <- partners published
//    t+1 <- partners polled/consumed t). So 2 parity buffers suffice for hg and parts.

#define BB 64
#define TT 1024
#define HH 512

typedef _Float16 half2_t __attribute__((ext_vector_type(2)));

__device__ __forceinline__ float dot2f(unsigned h, unsigned w, float acc) {
#if __has_builtin(__builtin_amdgcn_fdot2)
    return __builtin_amdgcn_fdot2(__builtin_bit_cast(half2_t, h),
                                  __builtin_bit_cast(half2_t, w), acc, false);
#else
    __half2 hh = __builtin_bit_cast(__half2, h);
    __half2 ww = __builtin_bit_cast(__half2, w);
    acc = fmaf(__low2float(hh), __low2float(ww), acc);
    return fmaf(__high2float(hh), __high2float(ww), acc);
#endif
}

__device__ __forceinline__ float fast_tanh(float z) {
    // tanh(z) = 1 - 2/(e^{2z}+1); exact identity, saturates correctly at +-inf
    float e = __expf(2.0f * z);
    return fmaf(-2.0f, __builtin_amdgcn_rcpf(e + 1.0f), 1.0f);
}

__launch_bounds__(256, 1)
__global__ void rnn_persist(const float* __restrict__ x,      // [B,T]
                            const float* __restrict__ W_ih,   // [H]
                            const float* __restrict__ W_hh,   // [H,H]
                            const float* __restrict__ b_ih,   // [H]
                            const float* __restrict__ b_hh,   // [H]
                            const float* __restrict__ W_out,  // [H]
                            const float* __restrict__ b_out,  // [1]
                            float* __restrict__ out,          // [64 + B*H]
                            unsigned long long* __restrict__ hg) // [2][B][4][64]
{
    const int q    = blockIdx.x >> 6;   // j-slice 0..3
    const int b    = blockIdx.x & 63;   // batch
    const int tid  = threadIdx.x;
    const int w    = tid >> 6;          // wave id = k-slice 0..3
    const int lane = tid & 63;

    __shared__ float parts[2][4][128];          // [parity][k-wave][local j]
    __shared__ float xrow[TT];                  // this batch's input row
    __shared__ __align__(16) unsigned h2w[4][64]; // per-wave private h slice

    // stage x row (barrier provided by first loop iteration's __syncthreads)
    for (int i = tid; i < TT; i += 256) xrow[i] = x[b * TT + i];

    // ---- weights: thread owns local j0=lane, j1=lane+64; k in [w*128, w*128+128)
    const int j0 = q * 128 + lane;
    const int j1 = j0 + 64;
    const int k0 = w * 128;
    unsigned wh0[64], wh1[64];
    {
        const float2* r0 = reinterpret_cast<const float2*>(W_hh + (size_t)j0 * HH + k0);
        const float2* r1 = reinterpret_cast<const float2*>(W_hh + (size_t)j1 * HH + k0);
#pragma unroll
        for (int d = 0; d < 64; ++d) {
            float2 a = r0[d], c = r1[d];
            wh0[d] = __builtin_bit_cast(unsigned, __floats2half2_rn(a.x, a.y));
            wh1[d] = __builtin_bit_cast(unsigned, __floats2half2_rn(c.x, c.y));
        }
    }

    // ---- publisher constants: lanes 0..15 of wave w own output slots 16w+lane
    const int s_slot = 16 * w + lane;     // valid when lane < 16
    float wihA = 0.f, wihB = 0.f, bA = 0.f, bB = 0.f;
    if (lane < 16) {
        const int ja = q * 128 + 2 * s_slot, jb = ja + 1;
        wihA = W_ih[ja]; wihB = W_ih[jb];
        bA = b_ih[ja] + b_hh[ja];
        bB = b_ih[jb] + b_hh[jb];
    }

#pragma unroll 1
    for (int t = 0; t < TT; ++t) {
        float a0 = 0.f, a1 = 0.f;
        if (t > 0) {
            // ---- poll slice w (tag t, parity t&1): one 8B relaxed atomic per lane
            const unsigned long long* pp =
                &hg[(((size_t)(t & 1) * BB + b) * 4 + w) * 64 + lane];
            unsigned long long v =
                __hip_atomic_load(pp, __ATOMIC_RELAXED, __HIP_MEMORY_SCOPE_AGENT);
            while ((unsigned)(v >> 32) != (unsigned)t) {
                __builtin_amdgcn_s_sleep(1);
                v = __hip_atomic_load(pp, __ATOMIC_RELAXED, __HIP_MEMORY_SCOPE_AGENT);
            }
            h2w[w][lane] = (unsigned)v;   // wave-private region: no barrier needed

            // ---- partials over this wave's 128-k slice (128 x v_dot2_f32_f16)
            const uint4* hp = reinterpret_cast<const uint4*>(&h2w[w][0]);
#pragma unroll
            for (int c = 0; c < 16; ++c) {
                const uint4 u = hp[c];
                a0 = dot2f(u.x, wh0[4*c+0], a0); a1 = dot2f(u.x, wh1[4*c+0], a1);
                a0 = dot2f(u.y, wh0[4*c+1], a0); a1 = dot2f(u.y, wh1[4*c+1], a1);
                a0 = dot2f(u.z, wh0[4*c+2], a0); a1 = dot2f(u.z, wh1[4*c+2], a1);
                a0 = dot2f(u.w, wh0[4*c+3], a0); a1 = dot2f(u.w, wh1[4*c+3], a1);
            }
        }
        parts[t & 1][w][lane]      = a0;
        parts[t & 1][w][lane + 64] = a1;
        __syncthreads();   // the ONLY barrier per step

        // ---- distributed reduce + tanh + publish (lanes 0..15 of every wave)
        if (lane < 16) {
            const float* pb = &parts[t & 1][0][0];
            const float2 p0 = *reinterpret_cast<const float2*>(pb + 0 * 128 + 2 * s_slot);
            const float2 p1 = *reinterpret_cast<const float2*>(pb + 1 * 128 + 2 * s_slot);
            const float2 p2 = *reinterpret_cast<const float2*>(pb + 2 * 128 + 2 * s_slot);
            const float2 p3 = *reinterpret_cast<const float2*>(pb + 3 * 128 + 2 * s_slot);
            float zA = (p0.x + p1.x) + (p2.x + p3.x);
            float zB = (p0.y + p1.y) + (p2.y + p3.y);
            const float xt = xrow[t];
            zA = fmaf(xt, wihA, zA + bA);
            zB = fmaf(xt, wihB, zB + bB);
            const float hA = fast_tanh(zA);
            const float hB = fast_tanh(zB);
            const unsigned d = __builtin_bit_cast(unsigned, __floats2half2_rn(hA, hB));
            const unsigned long long pv =
                ((unsigned long long)(unsigned)(t + 1) << 32) | d;
            __hip_atomic_store(
                &hg[(((size_t)((t + 1) & 1) * BB + b) * 4 + q) * 64 + s_slot], pv,
                __ATOMIC_RELAXED, __HIP_MEMORY_SCOPE_AGENT);
            if (t == TT - 1) {
                out[64 + b * HH + q * 128 + 2 * s_slot]     = hA;
                out[64 + b * HH + q * 128 + 2 * s_slot + 1] = hB;
            }
        }
    }

    // ---- epilogue: WG (b, q==0), wave 0 computes out[b] = h_last . W_out + b_out
    if (q == 0 && w == 0) {
        float s = 0.f;
#pragma unroll
        for (int sl = 0; sl < 4; ++sl) {
            const unsigned long long* pp =
                &hg[(((size_t)(TT & 1) * BB + b) * 4 + sl) * 64 + lane];
            unsigned long long v =
                __hip_atomic_load(pp, __ATOMIC_RELAXED, __HIP_MEMORY_SCOPE_AGENT);
            while ((unsigned)(v >> 32) != (unsigned)TT) {
                __builtin_amdgcn_s_sleep(1);
                v = __hip_atomic_load(pp, __ATOMIC_RELAXED, __HIP_MEMORY_SCOPE_AGENT);
            }
            const __half2 hh = __builtin_bit_cast(__half2, (unsigned)v);
            s = fmaf(__low2float(hh),  W_out[sl * 128 + 2 * lane],     s);
            s = fmaf(__high2float(hh), W_out[sl * 128 + 2 * lane + 1], s);
        }
#pragma unroll
        for (int off = 32; off; off >>= 1) s += __shfl_down(s, off, 64);
        if (lane == 0) out[b] = s + b_out[0];
    }
}

extern "C" void kernel_launch(void* const* d_in, const int* in_sizes, int n_in,
                              void* d_out, int out_size, void* d_ws, size_t ws_size,
                              hipStream_t stream) {
    const float* x     = (const float*)d_in[0];  // inputs [B,T,1]
    // d_in[1] = state (ignored; reference uses zero initial hidden state)
    const float* W_ih  = (const float*)d_in[2];
    const float* W_hh  = (const float*)d_in[3];
    const float* b_ih  = (const float*)d_in[4];
    const float* b_hh  = (const float*)d_in[5];
    const float* W_out = (const float*)d_in[6];
    const float* b_out = (const float*)d_in[7];

    unsigned long long* hg = (unsigned long long*)d_ws;  // [2][64][4][64] = 256 KB

    // tags must not alias garbage on the (unpoisoned) correctness call
    hipMemsetAsync(hg, 0, 2ull * BB * 4 * 64 * sizeof(unsigned long long), stream);

    rnn_persist<<<dim3(256), dim3(256), 0, stream>>>(
        x, W_ih, W_hh, b_ih, b_hh, W_out, b_out, (float*)d_out, hg);
}